// Round 4
// baseline (302.971 us; speedup 1.0000x reference)
//
#include <hip/hip_runtime.h>
#include <hip/hip_bf16.h>

// Single-head causal attention with value-residual mix.
// B=16, T=2048, C=768, H=64.  Inputs AND outputs are float32 (established
// round 3: inputs proven f32 via dtype probe; output proven f32 by the
// bf16-pairs-as-f32 error signature).  Internal compute: bf16 MFMA.
// Outputs (concat flat, f32): y=[B,T,64], then v1=[B,T,64].
//
// Storage: q(bf16) -> ws; k,v(bf16) -> output-1 region as scratch (exactly
// 2 x 4.19MB = its 8.39MB); y -> out0 f32 (disjoint); then d2d copy of f32
// v1 over the k/v scratch.

constexpr int BATCH = 16;
constexpr int TSEQ  = 2048;
constexpr int CEMB  = 768;
constexpr int HS    = 64;
constexpr size_t NTOK    = (size_t)BATCH * TSEQ;  // 32768
constexpr size_t OUTHALF = NTOK * HS;             // 2,097,152 elements

typedef __bf16 bf16x8 __attribute__((ext_vector_type(8)));
typedef float  f32x4  __attribute__((ext_vector_type(4)));

// ---------------------------------------------------------------------------
// Kernel 1: QKV projection.  k=x@Wk, q=x@Wq, v=(1-lamb)*(x@Wv)+lamb*v1
// Grid: (B*T)/64 blocks of 256 threads (4 waves x 16 rows each).
// ---------------------------------------------------------------------------
__global__ __launch_bounds__(256) void qkv_kernel(
    const float* __restrict__ x,      // [B*T, 768] f32
    const float* __restrict__ v1,     // [B*T, 64]  f32
    const float* __restrict__ wk,     // [768, 64]  f32
    const float* __restrict__ wq,
    const float* __restrict__ wv,
    const float* __restrict__ lamb_p, // [1] f32
    __bf16* __restrict__ kk,          // [B*T, 64] bf16
    __bf16* __restrict__ qq,
    __bf16* __restrict__ vv)
{
    __shared__ __bf16 wlds[3][HS][72];

    const int wave = threadIdx.x >> 6;
    const int lane = threadIdx.x & 63;
    const int l16  = lane & 15;
    const int quad = lane >> 4;
    const size_t row0 = (size_t)blockIdx.x * 64;

    const float* wmat[3] = {wk, wq, wv};

    f32x4 acc[3][4];
    #pragma unroll
    for (int m = 0; m < 3; ++m)
        #pragma unroll
        for (int nt = 0; nt < 4; ++nt)
            acc[m][nt] = (f32x4){0.f, 0.f, 0.f, 0.f};

    for (int c0 = 0; c0 < CEMB; c0 += 64) {
        __syncthreads();
        // Stage 3 W chunks [64c x 64h] transposed into wlds[m][h][c']
        for (int u = wave; u < 24; u += 4) {
            const int m  = u >> 3;
            const int cb = (u & 7) * 8;
            const float* wg = wmat[m] + (size_t)(c0 + cb) * HS + lane;
            bf16x8 tv;
            #pragma unroll
            for (int i = 0; i < 8; ++i) tv[i] = (__bf16)wg[(size_t)i * HS];
            *(bf16x8*)&wlds[m][lane][cb] = tv;
        }
        __syncthreads();

        // A-frags: x[m=l16][k=quad*8+j (+32 for xa1)]
        const float* xb = x + (row0 + wave * 16 + l16) * (size_t)CEMB + c0 + quad * 8;
        f32x4 a0 = *(const f32x4*)(xb);
        f32x4 a1 = *(const f32x4*)(xb + 4);
        f32x4 b0 = *(const f32x4*)(xb + 32);
        f32x4 b1 = *(const f32x4*)(xb + 36);
        bf16x8 xa0, xa1;
        #pragma unroll
        for (int i = 0; i < 4; ++i) {
            xa0[i]     = (__bf16)a0[i];
            xa0[i + 4] = (__bf16)a1[i];
            xa1[i]     = (__bf16)b0[i];
            xa1[i + 4] = (__bf16)b1[i];
        }

        #pragma unroll
        for (int m = 0; m < 3; ++m) {
            #pragma unroll
            for (int nt = 0; nt < 4; ++nt) {
                bf16x8 wf0 = *(const bf16x8*)&wlds[m][nt * 16 + l16][quad * 8];
                bf16x8 wf1 = *(const bf16x8*)&wlds[m][nt * 16 + l16][32 + quad * 8];
                acc[m][nt] = __builtin_amdgcn_mfma_f32_16x16x32_bf16(xa0, wf0, acc[m][nt], 0, 0, 0);
                acc[m][nt] = __builtin_amdgcn_mfma_f32_16x16x32_bf16(xa1, wf1, acc[m][nt], 0, 0, 0);
            }
        }
    }

    const float lam = lamb_p[0];

    // Epilogue: C/D layout col = l16 (+16*nt), row = quad*4 + r
    const size_t rbase = row0 + wave * 16 + quad * 4;
    #pragma unroll
    for (int nt = 0; nt < 4; ++nt) {
        #pragma unroll
        for (int r = 0; r < 4; ++r) {
            const size_t idx = (rbase + r) * HS + nt * 16 + l16;
            kk[idx] = (__bf16)acc[0][nt][r];
            qq[idx] = (__bf16)acc[1][nt][r];
            vv[idx] = (__bf16)((1.0f - lam) * acc[2][nt][r] + lam * v1[idx]);
        }
    }
}

// ---------------------------------------------------------------------------
// Kernel 2: flash attention + fused output projection.
// Grid: (B, T/64). Block 256 = 4 waves, each wave owns 16 q rows.
// q,k,v bf16; y written as FLOAT32 to out (disjoint from k/v scratch).
// ---------------------------------------------------------------------------
__global__ __launch_bounds__(256) void attn_kernel(
    const __bf16* __restrict__ q,      // [B*T, 64] bf16
    const __bf16* __restrict__ k,
    const __bf16* __restrict__ v,      // pre-mixed
    const float* __restrict__ wproj,   // [64, 64] f32
    const float* __restrict__ bproj,   // [64] f32
    float* __restrict__ y)             // [B*T, 64] f32
{
    __shared__ __bf16 vlds[HS][72];      // V^T tile: [h][s]
    __shared__ __bf16 plds[4][16][72];   // per-wave P/O staging [row][col]

    const int b    = blockIdx.x;
    const int qb   = blockIdx.y * 64;
    const int wave = threadIdx.x >> 6;
    const int lane = threadIdx.x & 63;
    const int l16  = lane & 15;
    const int quad = lane >> 4;

    const __bf16* qbase = q + ((size_t)b * TSEQ + qb + wave * 16 + l16) * HS + quad * 8;
    bf16x8 qf0 = *(const bf16x8*)(qbase);
    bf16x8 qf1 = *(const bf16x8*)(qbase + 32);

    f32x4 o_acc[4];
    #pragma unroll
    for (int nt = 0; nt < 4; ++nt) o_acc[nt] = (f32x4){0.f, 0.f, 0.f, 0.f};
    float m_i[4], l_i[4];
    #pragma unroll
    for (int r = 0; r < 4; ++r) { m_i[r] = -1e30f; l_i[r] = 0.f; }

    const float scale = 0.125f; // 1/sqrt(64)
    const int trow = qb + wave * 16 + quad * 4;

    for (int s0 = 0; s0 <= qb; s0 += 64) {
        __syncthreads();
        // Stage V^T tile
        {
            const int h = threadIdx.x & 63;
            for (int cc = (threadIdx.x >> 6); cc < 8; cc += 4) {
                const int sb = cc * 8;
                const __bf16* vg = v + ((size_t)b * TSEQ + s0 + sb) * HS + h;
                bf16x8 tv;
                #pragma unroll
                for (int i = 0; i < 8; ++i) tv[i] = vg[(size_t)i * HS];
                *(bf16x8*)&vlds[h][sb] = tv;
            }
        }
        __syncthreads();

        // S = Q K^T, K B-frags direct from global
        f32x4 sc[4];
        #pragma unroll
        for (int nt = 0; nt < 4; ++nt) {
            const __bf16* kbp = k + ((size_t)b * TSEQ + s0 + nt * 16 + l16) * HS + quad * 8;
            bf16x8 kf0 = *(const bf16x8*)(kbp);
            bf16x8 kf1 = *(const bf16x8*)(kbp + 32);
            f32x4 c = (f32x4){0.f, 0.f, 0.f, 0.f};
            c = __builtin_amdgcn_mfma_f32_16x16x32_bf16(qf0, kf0, c, 0, 0, 0);
            c = __builtin_amdgcn_mfma_f32_16x16x32_bf16(qf1, kf1, c, 0, 0, 0);
            sc[nt] = c;
        }

        float vals[4][4];
        if (s0 == qb) { // diagonal tile: mask s > t
            #pragma unroll
            for (int nt = 0; nt < 4; ++nt)
                #pragma unroll
                for (int r = 0; r < 4; ++r) {
                    const int s = s0 + nt * 16 + l16;
                    vals[nt][r] = (s <= trow + r) ? sc[nt][r] * scale : -1e30f;
                }
        } else {
            #pragma unroll
            for (int nt = 0; nt < 4; ++nt)
                #pragma unroll
                for (int r = 0; r < 4; ++r) vals[nt][r] = sc[nt][r] * scale;
        }

        // Online softmax (row r = quad*4+r, spread across the quad's 16 lanes)
        float mx[4];
        #pragma unroll
        for (int r = 0; r < 4; ++r) {
            mx[r] = fmaxf(fmaxf(vals[0][r], vals[1][r]), fmaxf(vals[2][r], vals[3][r]));
            #pragma unroll
            for (int off = 1; off < 16; off <<= 1)
                mx[r] = fmaxf(mx[r], __shfl_xor(mx[r], off));
        }
        float alpha[4];
        #pragma unroll
        for (int r = 0; r < 4; ++r) {
            const float mn = fmaxf(m_i[r], mx[r]);
            alpha[r] = __expf(m_i[r] - mn);
            m_i[r] = mn;
        }
        float rs[4] = {0.f, 0.f, 0.f, 0.f};
        float pv[4][4];
        #pragma unroll
        for (int nt = 0; nt < 4; ++nt)
            #pragma unroll
            for (int r = 0; r < 4; ++r) {
                const float p = __expf(vals[nt][r] - m_i[r]);
                pv[nt][r] = p;
                rs[r] += p;
            }
        #pragma unroll
        for (int r = 0; r < 4; ++r) {
            #pragma unroll
            for (int off = 1; off < 16; off <<= 1)
                rs[r] += __shfl_xor(rs[r], off);
            l_i[r] = l_i[r] * alpha[r] + rs[r];
        }
        #pragma unroll
        for (int nt = 0; nt < 4; ++nt)
            #pragma unroll
            for (int r = 0; r < 4; ++r) o_acc[nt][r] *= alpha[r];

        // P: C-layout -> A-layout via per-wave LDS round-trip
        #pragma unroll
        for (int nt = 0; nt < 4; ++nt)
            #pragma unroll
            for (int r = 0; r < 4; ++r)
                plds[wave][quad * 4 + r][nt * 16 + l16] = (__bf16)pv[nt][r];
        __syncthreads();

        // O += P V
        #pragma unroll
        for (int ks = 0; ks < 2; ++ks) {
            bf16x8 pf = *(const bf16x8*)&plds[wave][l16][ks * 32 + quad * 8];
            #pragma unroll
            for (int nt = 0; nt < 4; ++nt) {
                bf16x8 vf = *(const bf16x8*)&vlds[nt * 16 + l16][ks * 32 + quad * 8];
                o_acc[nt] = __builtin_amdgcn_mfma_f32_16x16x32_bf16(pf, vf, o_acc[nt], 0, 0, 0);
            }
        }
    }

    // Normalize, then fused projection: y = (O/l) @ Wproj + bproj
    float inv_l[4];
    #pragma unroll
    for (int r = 0; r < 4; ++r) inv_l[r] = 1.0f / l_i[r];

    __syncthreads();
    #pragma unroll
    for (int nt = 0; nt < 4; ++nt)
        #pragma unroll
        for (int r = 0; r < 4; ++r)
            plds[wave][quad * 4 + r][nt * 16 + l16] = (__bf16)(o_acc[nt][r] * inv_l[r]);
    __syncthreads();

    f32x4 res[4];
    #pragma unroll
    for (int nt = 0; nt < 4; ++nt) res[nt] = (f32x4){0.f, 0.f, 0.f, 0.f};
    #pragma unroll
    for (int ks = 0; ks < 2; ++ks) {
        bf16x8 of = *(const bf16x8*)&plds[wave][l16][ks * 32 + quad * 8];
        #pragma unroll
        for (int nt = 0; nt < 4; ++nt) {
            bf16x8 wf;
            #pragma unroll
            for (int i = 0; i < 8; ++i)
                wf[i] = (__bf16)wproj[(size_t)(ks * 32 + quad * 8 + i) * HS + nt * 16 + l16];
            res[nt] = __builtin_amdgcn_mfma_f32_16x16x32_bf16(of, wf, res[nt], 0, 0, 0);
        }
    }

    #pragma unroll
    for (int nt = 0; nt < 4; ++nt) {
        const float bp = bproj[nt * 16 + l16];
        #pragma unroll
        for (int r = 0; r < 4; ++r) {
            const size_t idx = ((size_t)b * TSEQ + qb + wave * 16 + quad * 4 + r) * HS + nt * 16 + l16;
            y[idx] = res[nt][r] + bp;   // FLOAT32 output
        }
    }
}

extern "C" void kernel_launch(void* const* d_in, const int* in_sizes, int n_in,
                              void* d_out, int out_size, void* d_ws, size_t ws_size,
                              hipStream_t stream) {
    const float* x     = (const float*)d_in[0];
    const float* v1    = (const float*)d_in[1];
    const float* wk    = (const float*)d_in[2];
    const float* wq    = (const float*)d_in[3];
    const float* wv    = (const float*)d_in[4];
    const float* wproj = (const float*)d_in[5];
    const float* bproj = (const float*)d_in[6];
    const float* lamb  = (const float*)d_in[7];

    float* out = (float*)d_out;               // [2 * OUTHALF] f32
    // bf16 scratch: q in ws; k,v exactly fill the output-1 f32 region (8.39MB).
    __bf16* qp = (__bf16*)d_ws;
    __bf16* kp = (__bf16*)(out + OUTHALF);
    __bf16* vp = kp + OUTHALF;

    qkv_kernel<<<dim3((int)(NTOK / 64)), dim3(256), 0, stream>>>(
        x, v1, wk, wq, wv, lamb, kp, qp, vp);

    attn_kernel<<<dim3(BATCH, TSEQ / 64), dim3(256), 0, stream>>>(
        qp, kp, vp, wproj, bproj, out);

    // Output 1: v1 passthrough (f32 -> f32), overwrites k/v scratch.
    hipMemcpyAsync(out + OUTHALF, v1, OUTHALF * sizeof(float),
                   hipMemcpyDeviceToDevice, stream);
}